// Round 5
// baseline (1155.556 us; speedup 1.0000x reference)
//
#include <hip/hip_runtime.h>

typedef __attribute__((ext_vector_type(8))) short short8;
typedef __attribute__((ext_vector_type(4))) float floatx4;

#define M_TOT 131072   // B*S = 64*2048
#define SEQ   2048
#define NB    8        // fallback n-tiles (1024/128)

__device__ __forceinline__ unsigned bf16rne(float x) {
  unsigned u = __float_as_uint(x);
  return (u + 0x7FFFu + ((u >> 16) & 1u)) >> 16;
}

#define GLOAD_LDS16(g, l) __builtin_amdgcn_global_load_lds( \
    (const __attribute__((address_space(1))) unsigned int*)(g), \
    (__attribute__((address_space(3))) unsigned int*)(l), 16, 0, 0)

#define VMW4 asm volatile("s_waitcnt vmcnt(4)" ::: "memory")
#define VMW2 asm volatile("s_waitcnt vmcnt(2)" ::: "memory")
#define VMW0 asm volatile("s_waitcnt vmcnt(0)" ::: "memory")
#define BAR() __builtin_amdgcn_s_barrier()
#define SP(n) __builtin_amdgcn_s_setprio(n)

// ---------------------------------------------------------------------------
// Convert enc fp32 -> bf16 in MFMA-FRAGMENT ORDER.
// Global chunk C = (mb*16 + t)*2048 + c, 16B each;
// c = h*1024 + wm*512 + mtl*128 + ks*64 + lane.
// Element e of chunk = enc[row, k]: row = mb*256 + wm*128 + (h*4+mtl)*16 +
// (lane&15); k = t*64 + ks*32 + (lane>>4)*8 + e.
// GEMM stages chunks linearly (gload_lds) -> LDS frag order -> all frag
// ds_read_b128 are lane-linear (zero bank conflicts).
// ---------------------------------------------------------------------------
__global__ __launch_bounds__(256) void convert_enc_frag_kernel(
    const float* __restrict__ in, unsigned int* __restrict__ out)
{
  unsigned C = blockIdx.x * 256 + threadIdx.x;     // 0..16777215
  int lane = C & 63, ks = (C >> 6) & 1, mtl = (C >> 7) & 3;
  int wm = (C >> 9) & 1, h = (C >> 10) & 1, t = (C >> 11) & 15;
  int mb = C >> 15;
  int row = mb * 256 + wm * 128 + (h * 4 + mtl) * 16 + (lane & 15);
  int k0 = t * 64 + ks * 32 + (lane >> 4) * 8;
  const float* p = in + (size_t)row * 1024 + k0;
  float4 a = *(const float4*)p;
  float4 b = *(const float4*)(p + 4);
  uint4 o;
  o.x = bf16rne(a.x) | (bf16rne(a.y) << 16);
  o.y = bf16rne(a.z) | (bf16rne(a.w) << 16);
  o.z = bf16rne(b.x) | (bf16rne(b.y) << 16);
  o.w = bf16rne(b.z) | (bf16rne(b.w) << 16);
  *(uint4*)(out + (size_t)C * 4) = o;
}

// ---------------------------------------------------------------------------
// Convert W1e fp32 -> bf16 in MFMA-FRAGMENT ORDER.
// G = (nb*16 + t)*2048 + c; c = h*1024 + wn*256 + ntl*128 + ks*64 + lane.
// d = nb*256 + wn*64 + (h*2+ntl)*16 + (lane&15); k = t*64+ks*32+(lane>>4)*8+e.
// ---------------------------------------------------------------------------
__global__ __launch_bounds__(256) void convert_w1e_frag_kernel(
    const float* __restrict__ W1, unsigned int* __restrict__ out)
{
  unsigned G = blockIdx.x * 256 + threadIdx.x;     // 0..131071
  int lane = G & 63, ks = (G >> 6) & 1, ntl = (G >> 7) & 1;
  int wn = (G >> 8) & 3, h = (G >> 10) & 1, t = (G >> 11) & 15;
  int nb = G >> 15;
  int d = nb * 256 + wn * 64 + (h * 2 + ntl) * 16 + (lane & 15);
  int k0 = t * 64 + ks * 32 + (lane >> 4) * 8;
  const float* p = W1 + (size_t)d * 2048 + k0;
  float4 a = *(const float4*)p;
  float4 b = *(const float4*)(p + 4);
  uint4 o;
  o.x = bf16rne(a.x) | (bf16rne(a.y) << 16);
  o.y = bf16rne(a.z) | (bf16rne(a.w) << 16);
  o.z = bf16rne(b.x) | (bf16rne(b.y) << 16);
  o.w = bf16rne(b.z) | (bf16rne(b.w) << 16);
  *(uint4*)(out + (size_t)G * 4) = o;
}

// ---------------------------------------------------------------------------
// Kernel 1: hvec[b,d] = b1[d] + sum_m hid[b,m] * W1[d, 1024+m]
// ---------------------------------------------------------------------------
__global__ __launch_bounds__(256) void hvec_kernel(
    const float* __restrict__ hid, const float* __restrict__ W1,
    const float* __restrict__ b1, float* __restrict__ hvec)
{
  int b = blockIdx.x, g = blockIdx.y;
  int w = threadIdx.x >> 6, lane = threadIdx.x & 63;
  const float* hrow = hid + b * 1024;
  for (int i = 0; i < 4; ++i) {
    int d = g * 16 + w * 4 + i;
    const float* wrow = W1 + (size_t)d * 2048 + 1024;
    float sum = 0.f;
#pragma unroll
    for (int c = 0; c < 4; ++c) {
      int m = c * 256 + lane * 4;
      float4 wv = *(const float4*)(wrow + m);
      float4 hv = *(const float4*)(hrow + m);
      sum += wv.x * hv.x + wv.y * hv.y + wv.z * hv.z + wv.w * hv.w;
    }
#pragma unroll
    for (int msk = 1; msk < 64; msk <<= 1) sum += __shfl_xor(sum, msk);
    if (lane == 0) hvec[b * 1024 + d] = sum + b1[d];
  }
}

// ---------------------------------------------------------------------------
// Kernel 2 (primary): 256x256, BK=64, 8-waves (2Mx4N), TRUE 8-phase pipeline.
// Per K-tile tau (slot s=tau&1), 4 phases; each phase:
//   stage ONE half-tile of tile tau+1 (2 gload_lds, frag-order, linear dest)
//   vmcnt(4)  [counted: completes stages <= 2 phases old; never 0 till tail]
//   s_barrier [publishes them]
//   ds_read frags needed ONE phase LATER (lane-linear, conflict-free)
//   setprio(1); 16 MFMA (operands read in a PREVIOUS phase); setprio(0)
// Stage order per tile: [A0, B0, B1, A1]; halves split by m-frag group
// (A0 = mt 0-3 both wm) / n-frag group (B0 = nt 0-1 all wn), so phase p
// consumes: p0:A0xB0 p1:A0xB1 p2:A1xB0 p3:A1xB1 (16 MFMA each).
// Legality: every read's data staged >=2 phases before its covering barrier;
// every slot write >=2 barriers after the slot's last read. A-frags share one
// register set (A0 dead after p1, A1 read at p2). LDS 128 KiB, 1 block/CU.
// ---------------------------------------------------------------------------
__global__ __launch_bounds__(512, 2) void gemm256_8ph_kernel(
    const unsigned short* __restrict__ encB, const unsigned short* __restrict__ W1eB,
    const float* __restrict__ W2, const float* __restrict__ hvec,
    float* __restrict__ epart)
{
  __shared__ __align__(16) unsigned short ldsA[2][16384];  // 64 KB (2 x 256x64)
  __shared__ __align__(16) unsigned short ldsB[2][16384];  // 64 KB

  const int tid = threadIdx.x;
  const int lid = blockIdx.x;            // 0..2047
  const int xcd = lid & 7, q = lid >> 3; // bijective XCD swizzle (2048%8==0)
  const int mb = xcd * 64 + (q >> 2);    // 0..511
  const int nb = q & 3;                  // 0..3
  const int r0 = mb * 256;
  const int bidx = mb >> 3;              // batch (8 m-tiles per batch row)
  const int wid = tid >> 6, lane = tid & 63;
  const int wm = wid >> 2, wn = wid & 3; // 2M x 4N waves, per-wave 128x64
  const int lrow = lane & 15;
  const int kq = lane >> 4;
  const int lane8 = lane * 8;

  floatx4 acc[8][4];
#pragma unroll
  for (int i = 0; i < 8; ++i)
#pragma unroll
    for (int j = 0; j < 4; ++j)
      acc[i][j] = (floatx4){0.f, 0.f, 0.f, 0.f};

#define STAGE_A(T, h, sl) do { \
    const unsigned short* gp = encB + ((size_t)(mb * 16 + (T)) * 2048 + (h) * 1024 + tid) * 8; \
    GLOAD_LDS16(gp,        &ldsA[sl][((h) * 1024 + wid * 64) * 8]); \
    GLOAD_LDS16(gp + 4096, &ldsA[sl][((h) * 1024 + 512 + wid * 64) * 8]); \
  } while (0)
#define STAGE_B(T, h, sl) do { \
    const unsigned short* gp = W1eB + ((size_t)(nb * 16 + (T)) * 2048 + (h) * 1024 + tid) * 8; \
    GLOAD_LDS16(gp,        &ldsB[sl][((h) * 1024 + wid * 64) * 8]); \
    GLOAD_LDS16(gp + 4096, &ldsB[sl][((h) * 1024 + 512 + wid * 64) * 8]); \
  } while (0)

  // frag read address bases (shorts): A: h*8192 + wm*4096 + mtl*1024 + ks*512
  //                                   B: h*8192 + wn*2048 + ntl*1024 + ks*512
  const int aRd = wm * 4096 + lane8;
  const int bRd = wn * 2048 + lane8;

  short8 af[4][2], b0[2][2], b1[2][2];

  // ---- prologue: tile 0 fully staged; read A0(0), B0(0) frags ----
  STAGE_A(0, 0, 0); STAGE_B(0, 0, 0); STAGE_B(0, 1, 0); STAGE_A(0, 1, 0);
  VMW4;                 // completes A0(0), B0(0)
  BAR();
#pragma unroll
  for (int mt = 0; mt < 4; ++mt)
#pragma unroll
    for (int ks = 0; ks < 2; ++ks)
      af[mt][ks] = *(const short8*)&ldsA[0][aRd + mt * 1024 + ks * 512];
#pragma unroll
  for (int nt = 0; nt < 2; ++nt)
#pragma unroll
    for (int ks = 0; ks < 2; ++ks)
      b0[nt][ks] = *(const short8*)&ldsB[0][bRd + nt * 1024 + ks * 512];

#define MFMA16(R, C, AF, BF) do { \
    SP(1); \
    _Pragma("unroll") for (int mt_ = 0; mt_ < 4; ++mt_) \
    _Pragma("unroll") for (int nt_ = 0; nt_ < 2; ++nt_) \
    _Pragma("unroll") for (int ks_ = 0; ks_ < 2; ++ks_) \
      acc[(R) + mt_][(C) + nt_] = __builtin_amdgcn_mfma_f32_16x16x32_bf16( \
          AF[mt_][ks_], BF[nt_][ks_], acc[(R) + mt_][(C) + nt_], 0, 0, 0); \
    SP(0); \
  } while (0)

  for (int tau = 0; tau < 16; ++tau) {
    const int s = tau & 1, sn = s ^ 1;
    const unsigned short* As = ldsA[s];
    const unsigned short* Bs = ldsB[s];
    const unsigned short* An = ldsA[sn];
    const unsigned short* Bn = ldsB[sn];
    const bool more = (tau < 15);

    // ---- phase 0 ---- stage A0(tau+1); read B1(tau); MFMA A0xB0
    if (more) { STAGE_A(tau + 1, 0, sn); VMW4; } else { VMW2; }
    BAR();
#pragma unroll
    for (int nt = 0; nt < 2; ++nt)
#pragma unroll
      for (int ks = 0; ks < 2; ++ks)
        b1[nt][ks] = *(const short8*)&Bs[8192 + bRd + nt * 1024 + ks * 512];
    MFMA16(0, 0, af, b0);

    // ---- phase 1 ---- stage B0(tau+1); MFMA A0xB1
    if (more) { STAGE_B(tau + 1, 0, sn); VMW4; } else { VMW0; }
    BAR();
    MFMA16(0, 2, af, b1);

    // ---- phase 2 ---- stage B1(tau+1); read A1(tau); MFMA A1xB0
    if (more) { STAGE_B(tau + 1, 1, sn); VMW4; }
    BAR();
#pragma unroll
    for (int mt = 0; mt < 4; ++mt)
#pragma unroll
      for (int ks = 0; ks < 2; ++ks)
        af[mt][ks] = *(const short8*)&As[8192 + aRd + mt * 1024 + ks * 512];
    MFMA16(4, 0, af, b0);

    // ---- phase 3 ---- stage A1(tau+1); read B0(tau+1); MFMA A1xB1; read A0(tau+1)
    if (more) { STAGE_A(tau + 1, 1, sn); VMW4; }
    BAR();
    if (more) {
#pragma unroll
      for (int nt = 0; nt < 2; ++nt)
#pragma unroll
        for (int ks = 0; ks < 2; ++ks)
          b0[nt][ks] = *(const short8*)&Bn[bRd + nt * 1024 + ks * 512];
    }
    MFMA16(4, 2, af, b1);
    if (more) {
#pragma unroll
      for (int mt = 0; mt < 4; ++mt)
#pragma unroll
        for (int ks = 0; ks < 2; ++ks)
          af[mt][ks] = *(const short8*)&An[aRd + mt * 1024 + ks * 512];
    }
  }
#undef MFMA16
#undef STAGE_A
#undef STAGE_B

  // ---- epilogue: tanh + W2-dot -> epart plane nb ----
  __syncthreads();
  float* ep = (float*)&ldsA[0][0];   // [4 wn][256 m] floats
  float hv[4], w2v[4];
#pragma unroll
  for (int nt = 0; nt < 4; ++nt) {
    int n = nb * 256 + wn * 64 + nt * 16 + lrow;
    hv[nt]  = hvec[bidx * 1024 + n];
    w2v[nt] = W2[n];
  }
#pragma unroll
  for (int mt = 0; mt < 8; ++mt) {
#pragma unroll
    for (int r = 0; r < 4; ++r) {
      float sum = 0.f;
#pragma unroll
      for (int nt = 0; nt < 4; ++nt) {
        float pre = acc[mt][nt][r] + hv[nt];
        float ex = __expf(2.f * pre);
        sum += (1.f - 2.f / (ex + 1.f)) * w2v[nt];
      }
      sum += __shfl_xor(sum, 1);
      sum += __shfl_xor(sum, 2);
      sum += __shfl_xor(sum, 4);
      sum += __shfl_xor(sum, 8);
      if (lrow == 0) ep[wn * 256 + wm * 128 + mt * 16 + kq * 4 + r] = sum;
    }
  }
  __syncthreads();
  if (tid < 256) {
    float sv = ep[tid] + ep[256 + tid] + ep[512 + tid] + ep[768 + tid];
    epart[(size_t)nb * M_TOT + r0 + tid] = sv;
  }
}

// ---------------------------------------------------------------------------
// Kernel 2 (fallback, no-ws path): fused GEMM with in-loop convert (128-tile).
// ---------------------------------------------------------------------------
__global__ __launch_bounds__(256) void fused_gemm_kernel(
    const float* __restrict__ enc, const float* __restrict__ W1,
    const float* __restrict__ W2, const float* __restrict__ hvec,
    float* __restrict__ epart)
{
  __shared__ __align__(16) unsigned short Ah[128 * 32];
  __shared__ __align__(16) unsigned short Bh[128 * 32];
  __shared__ float ep[2][128];

  const int tid = threadIdx.x;
  const int nb = blockIdx.x, mb = blockIdx.y;
  const int r0 = mb * 128, n0 = nb * 128;
  const int bidx = r0 >> 11;
  const int w = tid >> 6, lane = tid & 63;
  const int wm = w >> 1, wn = w & 1;
  const int lrow = lane & 15, kq = lane >> 4;

  floatx4 acc[4][4];
#pragma unroll
  for (int i = 0; i < 4; ++i)
#pragma unroll
    for (int j = 0; j < 4; ++j)
      acc[i][j] = (floatx4){0.f, 0.f, 0.f, 0.f};

  const int srow = tid >> 3;
  const int scol = (tid & 7) * 4;
  const float* aptr = enc + (size_t)(r0 + srow) * 1024 + scol;
  const float* bptr = W1  + (size_t)(n0 + srow) * 2048 + scol;

  for (int k0 = 0; k0 < 1024; k0 += 32) {
    float4 av[4], bv[4];
#pragma unroll
    for (int j = 0; j < 4; ++j) {
      av[j] = *(const float4*)(aptr + (size_t)(j * 32) * 1024 + k0);
      bv[j] = *(const float4*)(bptr + (size_t)(j * 32) * 2048 + k0);
    }
    __syncthreads();
#pragma unroll
    for (int j = 0; j < 4; ++j) {
      unsigned ax = __float_as_uint(av[j].x), ay = __float_as_uint(av[j].y);
      unsigned az = __float_as_uint(av[j].z), aw = __float_as_uint(av[j].w);
      unsigned a01 = __builtin_amdgcn_perm(ay, ax, 0x07060302u);
      unsigned a23 = __builtin_amdgcn_perm(aw, az, 0x07060302u);
      *(uint2*)&Ah[(tid + j * 256) * 4] = make_uint2(a01, a23);
      unsigned bx = __float_as_uint(bv[j].x), by = __float_as_uint(bv[j].y);
      unsigned bz = __float_as_uint(bv[j].z), bw = __float_as_uint(bv[j].w);
      unsigned b01 = __builtin_amdgcn_perm(by, bx, 0x07060302u);
      unsigned b23 = __builtin_amdgcn_perm(bw, bz, 0x07060302u);
      *(uint2*)&Bh[(tid + j * 256) * 4] = make_uint2(b01, b23);
    }
    __syncthreads();

    short8 af[4], bfm[4];
#pragma unroll
    for (int t4 = 0; t4 < 4; ++t4) {
      af[t4]  = *(const short8*)&Ah[(wm * 64 + t4 * 16 + lrow) * 32 + kq * 8];
      bfm[t4] = *(const short8*)&Bh[(wn * 64 + t4 * 16 + lrow) * 32 + kq * 8];
    }
#pragma unroll
    for (int mt = 0; mt < 4; ++mt)
#pragma unroll
      for (int nt = 0; nt < 4; ++nt)
        acc[mt][nt] = __builtin_amdgcn_mfma_f32_16x16x32_bf16(
            af[mt], bfm[nt], acc[mt][nt], 0, 0, 0);
  }

  float hv[4], w2v[4];
#pragma unroll
  for (int nt = 0; nt < 4; ++nt) {
    int n = n0 + wn * 64 + nt * 16 + lrow;
    hv[nt]  = hvec[bidx * 1024 + n];
    w2v[nt] = W2[n];
  }
#pragma unroll
  for (int mt = 0; mt < 4; ++mt) {
#pragma unroll
    for (int r = 0; r < 4; ++r) {
      float sum = 0.f;
#pragma unroll
      for (int nt = 0; nt < 4; ++nt) {
        float pre = acc[mt][nt][r] + hv[nt];
        float ex = __expf(2.f * pre);
        sum += (1.f - 2.f / (ex + 1.f)) * w2v[nt];
      }
      sum += __shfl_xor(sum, 1);
      sum += __shfl_xor(sum, 2);
      sum += __shfl_xor(sum, 4);
      sum += __shfl_xor(sum, 8);
      if (lrow == 0) ep[wn][wm * 64 + mt * 16 + kq * 4 + r] = sum;
    }
  }
  __syncthreads();
  if (tid < 128)
    epart[(size_t)nb * M_TOT + r0 + tid] = ep[0][tid] + ep[1][tid];
}

// ---------------------------------------------------------------------------
// Kernel 3: softmax over S per batch. NP = number of epart planes.
// ---------------------------------------------------------------------------
template<int NP>
__global__ __launch_bounds__(256) void softmax_kernel(
    const float* __restrict__ epart, float* __restrict__ alpha)
{
  int b = blockIdx.x, t = threadIdx.x;
  __shared__ float redmax[4], redsum[4];
  float ev[8];
  float lmax = -1e30f;
#pragma unroll
  for (int j = 0; j < 8; ++j) {
    int s = t + j * 256;
    float sum = 0.f;
#pragma unroll
    for (int p = 0; p < NP; ++p) sum += epart[(size_t)p * M_TOT + b * SEQ + s];
    ev[j] = sum;
    lmax = fmaxf(lmax, sum);
  }
#pragma unroll
  for (int msk = 1; msk < 64; msk <<= 1) lmax = fmaxf(lmax, __shfl_xor(lmax, msk));
  if ((t & 63) == 0) redmax[t >> 6] = lmax;
  __syncthreads();
  float bmax = fmaxf(fmaxf(redmax[0], redmax[1]), fmaxf(redmax[2], redmax[3]));
  float lsum = 0.f;
#pragma unroll
  for (int j = 0; j < 8; ++j) { ev[j] = __expf(ev[j] - bmax); lsum += ev[j]; }
#pragma unroll
  for (int msk = 1; msk < 64; msk <<= 1) lsum += __shfl_xor(lsum, msk);
  if ((t & 63) == 0) redsum[t >> 6] = lsum;
  __syncthreads();
  float inv = 1.f / (redsum[0] + redsum[1] + redsum[2] + redsum[3]);
#pragma unroll
  for (int j = 0; j < 8; ++j) alpha[b * SEQ + t + j * 256] = ev[j] * inv;
}

// ---------------------------------------------------------------------------
// Kernel 4 (primary): context from fp32 enc, atomic-free. grid (64,8) x 512.
// ---------------------------------------------------------------------------
__global__ __launch_bounds__(512) void context_f32_kernel(
    const float* __restrict__ enc, const float* __restrict__ alpha,
    float* __restrict__ out)
{
  __shared__ float red[16][128];
  int b = blockIdx.x, kc = blockIdx.y, t = threadIdx.x;
  int kl = (t & 31) * 4;              // k-local 0..124
  int strip = t >> 5;                 // 0..15
  const float* ep = enc + ((size_t)b * SEQ + strip * 128) * 1024 + kc * 128 + kl;
  const float* ap = alpha + b * SEQ + strip * 128;
  float a0 = 0.f, a1 = 0.f, a2 = 0.f, a3 = 0.f;
#pragma unroll 4
  for (int s = 0; s < 128; ++s) {
    float a = ap[s];
    float4 v = *(const float4*)(ep + (size_t)s * 1024);
    a0 += a * v.x; a1 += a * v.y; a2 += a * v.z; a3 += a * v.w;
  }
  red[strip][kl + 0] = a0;
  red[strip][kl + 1] = a1;
  red[strip][kl + 2] = a2;
  red[strip][kl + 3] = a3;
  __syncthreads();
  if (t < 128) {
    float s = 0.f;
#pragma unroll
    for (int j = 0; j < 16; ++j) s += red[j][t];
    out[b * 1024 + kc * 128 + t] = s;
  }
}

// ---------------------------------------------------------------------------
// Kernel 4 (fallback): fp32 context with atomics.
// ---------------------------------------------------------------------------
__global__ __launch_bounds__(256) void context_kernel(
    const float* __restrict__ enc, const float* __restrict__ alpha,
    float* __restrict__ out)
{
  int b = blockIdx.y, sq = blockIdx.z, t = threadIdx.x;
  int k4 = t * 4;
  const float* ep = enc + ((size_t)b * SEQ + sq * 128) * 1024 + k4;
  const float* ap = alpha + b * SEQ + sq * 128;
  float ax = 0.f, ay = 0.f, az = 0.f, aw = 0.f;
#pragma unroll 4
  for (int s = 0; s < 128; ++s) {
    float a = ap[s];
    float4 v = *(const float4*)(ep + (size_t)s * 1024);
    ax += a * v.x; ay += a * v.y; az += a * v.z; aw += a * v.w;
  }
  float* o = out + b * 1024 + k4;
  atomicAdd(o + 0, ax);
  atomicAdd(o + 1, ay);
  atomicAdd(o + 2, az);
  atomicAdd(o + 3, aw);
}

// ---------------------------------------------------------------------------
extern "C" void kernel_launch(void* const* d_in, const int* in_sizes, int n_in,
                              void* d_out, int out_size, void* d_ws, size_t ws_size,
                              hipStream_t stream) {
  const float* hid = (const float*)d_in[0];
  const float* enc = (const float*)d_in[1];
  const float* W1  = (const float*)d_in[2];
  const float* b1  = (const float*)d_in[3];
  const float* W2  = (const float*)d_in[4];
  float* out = (float*)d_out;

  float* epart = (float*)d_ws;                       // NB * M_TOT planes (max)
  float* alpha = epart + (size_t)NB * M_TOT;         // M_TOT
  float* hvec  = alpha + M_TOT;                      // 64*1024
  size_t small_bytes = ((size_t)NB * M_TOT + M_TOT + 64 * 1024) * 4;
  size_t encB_off = ((small_bytes + 255) / 256) * 256;
  size_t need = encB_off + (size_t)M_TOT * 1024 * 2 + (size_t)1024 * 1024 * 2;

  hvec_kernel<<<dim3(64, 64), 256, 0, stream>>>(hid, W1, b1, hvec);

  if (ws_size >= need) {
    unsigned short* encB = (unsigned short*)((char*)d_ws + encB_off);
    unsigned short* W1eB = encB + (size_t)M_TOT * 1024;
    convert_enc_frag_kernel<<<65536, 256, 0, stream>>>(enc, (unsigned int*)encB);
    convert_w1e_frag_kernel<<<512, 256, 0, stream>>>(W1, (unsigned int*)W1eB);
    gemm256_8ph_kernel<<<2048, 512, 0, stream>>>(encB, W1eB, W2, hvec, epart);
    softmax_kernel<4><<<64, 256, 0, stream>>>(epart, alpha);
    context_f32_kernel<<<dim3(64, 8), 512, 0, stream>>>(enc, alpha, out);
  } else {
    hipMemsetAsync(d_out, 0, (size_t)out_size * sizeof(float), stream);
    fused_gemm_kernel<<<dim3(NB, 1024), 256, 0, stream>>>(enc, W1, W2, hvec, epart);
    softmax_kernel<8><<<64, 256, 0, stream>>>(epart, alpha);
    context_kernel<<<dim3(1, 64, 16), 256, 0, stream>>>(enc, alpha, out);
  }
}

// Round 6
// 1137.366 us; speedup vs baseline: 1.0160x; 1.0160x over previous
//
#include <hip/hip_runtime.h>

typedef __attribute__((ext_vector_type(8))) short short8;
typedef __attribute__((ext_vector_type(4))) float floatx4;

#define M_TOT 131072   // B*S = 64*2048
#define SEQ   2048
#define NB    8        // n-tiles (1024/128), both paths

__device__ __forceinline__ unsigned bf16rne(float x) {
  unsigned u = __float_as_uint(x);
  return (u + 0x7FFFu + ((u >> 16) & 1u)) >> 16;
}

#define GLOAD_LDS16(g, l) __builtin_amdgcn_global_load_lds( \
    (const __attribute__((address_space(1))) unsigned int*)(g), \
    (__attribute__((address_space(3))) unsigned int*)(l), 16, 0, 0)

// ---------------------------------------------------------------------------
// Convert enc fp32 -> bf16 in MFMA-FRAGMENT ORDER for the 256x128 GEMM.
// Chunk C = (mb*32 + t)*1024 + c; c = (wm*4 + mt)*64 + l  (16B chunks).
// Element e of chunk: row = mb*256 + wm*64 + mt*16 + (l&15),
//                     k   = t*32 + (l>>4)*8 + e.
// GEMM stages chunks linearly with gload_lds -> LDS holds frag order ->
// every fragment ds_read_b128 is lane-linear (zero bank conflicts).
// ---------------------------------------------------------------------------
__global__ __launch_bounds__(256) void convert_enc_frag_kernel(
    const float* __restrict__ in, unsigned int* __restrict__ out)
{
  unsigned C = blockIdx.x * 256 + threadIdx.x;     // 0..16777215
  int l = C & 63, mt = (C >> 6) & 3, wm = (C >> 8) & 3;
  int t = (C >> 10) & 31, mb = C >> 15;
  int row = mb * 256 + wm * 64 + mt * 16 + (l & 15);
  int k0  = t * 32 + (l >> 4) * 8;
  const float* p = in + (size_t)row * 1024 + k0;
  float4 a = *(const float4*)p;
  float4 b = *(const float4*)(p + 4);
  uint4 o;
  o.x = bf16rne(a.x) | (bf16rne(a.y) << 16);
  o.y = bf16rne(a.z) | (bf16rne(a.w) << 16);
  o.z = bf16rne(b.x) | (bf16rne(b.y) << 16);
  o.w = bf16rne(b.z) | (bf16rne(b.w) << 16);
  *(uint4*)(out + (size_t)C * 4) = o;
}

// ---------------------------------------------------------------------------
// Convert W1e fp32 -> bf16 in MFMA-FRAGMENT ORDER.
// Chunk G = (nb*32 + t)*512 + c; c = (wn*4 + nt)*64 + l.
// d = nb*128 + wn*64 + nt*16 + (l&15); k = t*32 + (l>>4)*8 + e.
// ---------------------------------------------------------------------------
__global__ __launch_bounds__(256) void convert_w1e_frag_kernel(
    const float* __restrict__ W1, unsigned int* __restrict__ out)
{
  unsigned G = blockIdx.x * 256 + threadIdx.x;     // 0..131071
  int l = G & 63, nt = (G >> 6) & 3, wn = (G >> 8) & 1;
  int t = (G >> 9) & 31, nb = G >> 14;
  int d  = nb * 128 + wn * 64 + nt * 16 + (l & 15);
  int k0 = t * 32 + (l >> 4) * 8;
  const float* p = W1 + (size_t)d * 2048 + k0;
  float4 a = *(const float4*)p;
  float4 b = *(const float4*)(p + 4);
  uint4 o;
  o.x = bf16rne(a.x) | (bf16rne(a.y) << 16);
  o.y = bf16rne(a.z) | (bf16rne(a.w) << 16);
  o.z = bf16rne(b.x) | (bf16rne(b.y) << 16);
  o.w = bf16rne(b.z) | (bf16rne(b.w) << 16);
  *(uint4*)(out + (size_t)G * 4) = o;
}

// ---------------------------------------------------------------------------
// Kernel 1: hvec[b,d] = b1[d] + sum_m hid[b,m] * W1[d, 1024+m]
// ---------------------------------------------------------------------------
__global__ __launch_bounds__(256) void hvec_kernel(
    const float* __restrict__ hid, const float* __restrict__ W1,
    const float* __restrict__ b1, float* __restrict__ hvec)
{
  int b = blockIdx.x, g = blockIdx.y;
  int w = threadIdx.x >> 6, lane = threadIdx.x & 63;
  const float* hrow = hid + b * 1024;
  for (int i = 0; i < 4; ++i) {
    int d = g * 16 + w * 4 + i;
    const float* wrow = W1 + (size_t)d * 2048 + 1024;
    float sum = 0.f;
#pragma unroll
    for (int c = 0; c < 4; ++c) {
      int m = c * 256 + lane * 4;
      float4 wv = *(const float4*)(wrow + m);
      float4 hv = *(const float4*)(hrow + m);
      sum += wv.x * hv.x + wv.y * hv.y + wv.z * hv.z + wv.w * hv.w;
    }
#pragma unroll
    for (int msk = 1; msk < 64; msk <<= 1) sum += __shfl_xor(sum, msk);
    if (lane == 0) hvec[b * 1024 + d] = sum + b1[d];
  }
}

// ---------------------------------------------------------------------------
// Kernel 2 (primary): 256x128 tile, BK=32, 8 waves (4M x 2N, 64x64/wave),
// 2 BLOCKS/CU (LDS 72 KB, <=128 VGPR via __launch_bounds__(512,4)).
// Rationale: all 1-block/CU 256^2 schedules pinned at MfmaUtil 34-36%
// regardless of pipeline structure (R1/R2/R3/R5); the missing mechanism is
// cross-block wave overlap (m114/m97) -- a second resident block fills the
// CU during this block's barrier/DMA stalls.
// Ring-3 slots, counted vmcnt(3) (1-tile lead), one barrier/tile.
// Slot-write safety: stage(t+1) -> slot (t+1)%3, whose last readers (tile
// t-2) finished their reads before MFMA(t-2) (lgkm) and hence before
// arriving at barrier(t-1); stage(t+1) issues only after passing
// barrier(t-1). Frag-order layout -> all ds_read_b128 lane-linear, 0 conflicts.
// ---------------------------------------------------------------------------
__global__ __launch_bounds__(512, 4) void gemm256x128_kernel(
    const unsigned short* __restrict__ encB, const unsigned short* __restrict__ W1eB,
    const float* __restrict__ W2, const float* __restrict__ hvec,
    float* __restrict__ epart)
{
  __shared__ __align__(16) unsigned short ldsA[3][8192];   // 48 KB (3 x 256x32)
  __shared__ __align__(16) unsigned short ldsB[3][4096];   // 24 KB (3 x 128x32)

  const int tid = threadIdx.x;
  const int lid = blockIdx.x;            // 0..4095
  const int xcd = lid & 7, q = lid >> 3; // bijective XCD swizzle (4096%8==0)
  const int mb = xcd * 64 + (q >> 3);    // 0..511
  const int nb = q & 7;                  // 0..7
  const int r0 = mb * 256;
  const int bidx = mb >> 3;              // batch (256 divides S=2048)
  const int wid = tid >> 6, lane = tid & 63;
  const int wm = wid >> 1, wn = wid & 1; // 4M x 2N waves, per-wave 64x64
  const int lrow = lane & 15, kq = lane >> 4;
  const int lane8 = lane * 8;

  floatx4 acc[4][4];
#pragma unroll
  for (int i = 0; i < 4; ++i)
#pragma unroll
    for (int j = 0; j < 4; ++j)
      acc[i][j] = (floatx4){0.f, 0.f, 0.f, 0.f};

  unsigned short *aCur = ldsA[0], *aNx = ldsA[1], *aN2 = ldsA[2];
  unsigned short *bCur = ldsB[0], *bNx = ldsB[1], *bN2 = ldsB[2];

  // prologue: stage tile 0 (3 gloads/thread) into slot 0
  {
    const unsigned short* ga = encB + ((size_t)mb * 32 * 1024 + tid) * 8;
    GLOAD_LDS16(ga,        &aCur[wid * 512]);
    GLOAD_LDS16(ga + 4096, &aCur[4096 + wid * 512]);
    const unsigned short* gb = W1eB + ((size_t)nb * 32 * 512 + tid) * 8;
    GLOAD_LDS16(gb,        &bCur[wid * 512]);
  }

  const int aRd = wm * 2048 + lane8;   // + mt*512
  const int bRd = wn * 2048 + lane8;   // + nt*512

  for (int t = 0; t < 32; ++t) {
    if (t < 31) {
      const unsigned short* ga = encB + ((size_t)(mb * 32 + t + 1) * 1024 + tid) * 8;
      GLOAD_LDS16(ga,        &aNx[wid * 512]);
      GLOAD_LDS16(ga + 4096, &aNx[4096 + wid * 512]);
      const unsigned short* gb = W1eB + ((size_t)(nb * 32 + t + 1) * 512 + tid) * 8;
      GLOAD_LDS16(gb,        &bNx[wid * 512]);
      asm volatile("s_waitcnt vmcnt(3)" ::: "memory");   // tile t landed
    } else {
      asm volatile("s_waitcnt vmcnt(0)" ::: "memory");
    }
    __builtin_amdgcn_s_barrier();                        // publish tile t

    short8 af[4], bf[4];
#pragma unroll
    for (int mt = 0; mt < 4; ++mt) af[mt] = *(const short8*)&aCur[aRd + mt * 512];
#pragma unroll
    for (int nt = 0; nt < 4; ++nt) bf[nt] = *(const short8*)&bCur[bRd + nt * 512];
    __builtin_amdgcn_s_setprio(1);
#pragma unroll
    for (int mt = 0; mt < 4; ++mt)
#pragma unroll
      for (int nt = 0; nt < 4; ++nt)
        acc[mt][nt] = __builtin_amdgcn_mfma_f32_16x16x32_bf16(
            af[mt], bf[nt], acc[mt][nt], 0, 0, 0);
    __builtin_amdgcn_s_setprio(0);

    unsigned short* tA = aCur; aCur = aNx; aNx = aN2; aN2 = tA;
    unsigned short* tB = bCur; bCur = bNx; bNx = bN2; bN2 = tB;
  }

  // epilogue: tanh + W2-dot -> epart plane nb. All DMA drained (vmcnt(0)).
  __syncthreads();
  float* ep = (float*)&ldsA[0][0];   // [2 wn][256 m] floats (2 KB)
  float hv[4], w2v[4];
#pragma unroll
  for (int nt = 0; nt < 4; ++nt) {
    int n = nb * 128 + wn * 64 + nt * 16 + lrow;
    hv[nt]  = hvec[bidx * 1024 + n];
    w2v[nt] = W2[n];
  }
#pragma unroll
  for (int mt = 0; mt < 4; ++mt) {
#pragma unroll
    for (int r = 0; r < 4; ++r) {
      float sum = 0.f;
#pragma unroll
      for (int nt = 0; nt < 4; ++nt) {
        float pre = acc[mt][nt][r] + hv[nt];
        float ex = __expf(2.f * pre);
        sum += (1.f - 2.f / (ex + 1.f)) * w2v[nt];
      }
      sum += __shfl_xor(sum, 1);
      sum += __shfl_xor(sum, 2);
      sum += __shfl_xor(sum, 4);
      sum += __shfl_xor(sum, 8);
      if (lrow == 0) ep[wn * 256 + wm * 64 + mt * 16 + kq * 4 + r] = sum;
    }
  }
  __syncthreads();
  if (tid < 256)
    epart[(size_t)nb * M_TOT + r0 + tid] = ep[tid] + ep[256 + tid];
}

// ---------------------------------------------------------------------------
// Kernel 2 (fallback, no-ws path): fused GEMM with in-loop convert (128-tile).
// ---------------------------------------------------------------------------
__global__ __launch_bounds__(256) void fused_gemm_kernel(
    const float* __restrict__ enc, const float* __restrict__ W1,
    const float* __restrict__ W2, const float* __restrict__ hvec,
    float* __restrict__ epart)
{
  __shared__ __align__(16) unsigned short Ah[128 * 32];
  __shared__ __align__(16) unsigned short Bh[128 * 32];
  __shared__ float ep[2][128];

  const int tid = threadIdx.x;
  const int nb = blockIdx.x, mb = blockIdx.y;
  const int r0 = mb * 128, n0 = nb * 128;
  const int bidx = r0 >> 11;
  const int w = tid >> 6, lane = tid & 63;
  const int wm = w >> 1, wn = w & 1;
  const int lrow = lane & 15, kq = lane >> 4;

  floatx4 acc[4][4];
#pragma unroll
  for (int i = 0; i < 4; ++i)
#pragma unroll
    for (int j = 0; j < 4; ++j)
      acc[i][j] = (floatx4){0.f, 0.f, 0.f, 0.f};

  const int srow = tid >> 3;
  const int scol = (tid & 7) * 4;
  const float* aptr = enc + (size_t)(r0 + srow) * 1024 + scol;
  const float* bptr = W1  + (size_t)(n0 + srow) * 2048 + scol;

  for (int k0 = 0; k0 < 1024; k0 += 32) {
    float4 av[4], bv[4];
#pragma unroll
    for (int j = 0; j < 4; ++j) {
      av[j] = *(const float4*)(aptr + (size_t)(j * 32) * 1024 + k0);
      bv[j] = *(const float4*)(bptr + (size_t)(j * 32) * 2048 + k0);
    }
    __syncthreads();
#pragma unroll
    for (int j = 0; j < 4; ++j) {
      unsigned ax = __float_as_uint(av[j].x), ay = __float_as_uint(av[j].y);
      unsigned az = __float_as_uint(av[j].z), aw = __float_as_uint(av[j].w);
      unsigned a01 = __builtin_amdgcn_perm(ay, ax, 0x07060302u);
      unsigned a23 = __builtin_amdgcn_perm(aw, az, 0x07060302u);
      *(uint2*)&Ah[(tid + j * 256) * 4] = make_uint2(a01, a23);
      unsigned bx = __float_as_uint(bv[j].x), by = __float_as_uint(bv[j].y);
      unsigned bz = __float_as_uint(bv[j].z), bw = __float_as_uint(bv[j].w);
      unsigned b01 = __builtin_amdgcn_perm(by, bx, 0x07060302u);
      unsigned b23 = __builtin_amdgcn_perm(bw, bz, 0x07060302u);
      *(uint2*)&Bh[(tid + j * 256) * 4] = make_uint2(b01, b23);
    }
    __syncthreads();

    short8 af[4], bfm[4];
#pragma unroll
    for (int t4 = 0; t4 < 4; ++t4) {
      af[t4]  = *(const short8*)&Ah[(wm * 64 + t4 * 16 + lrow) * 32 + kq * 8];
      bfm[t4] = *(const short8*)&Bh[(wn * 64 + t4 * 16 + lrow) * 32 + kq * 8];
    }
#pragma unroll
    for (int mt = 0; mt < 4; ++mt)
#pragma unroll
      for (int nt = 0; nt < 4; ++nt)
        acc[mt][nt] = __builtin_amdgcn_mfma_f32_16x16x32_bf16(
            af[mt], bfm[nt], acc[mt][nt], 0, 0, 0);
  }

  float hv[4], w2v[4];
#pragma unroll
  for (int nt = 0; nt < 4; ++nt) {
    int n = n0 + wn * 64 + nt * 16 + lrow;
    hv[nt]  = hvec[bidx * 1024 + n];
    w2v[nt] = W2[n];
  }
#pragma unroll
  for (int mt = 0; mt < 4; ++mt) {
#pragma unroll
    for (int r = 0; r < 4; ++r) {
      float sum = 0.f;
#pragma unroll
      for (int nt = 0; nt < 4; ++nt) {
        float pre = acc[mt][nt][r] + hv[nt];
        float ex = __expf(2.f * pre);
        sum += (1.f - 2.f / (ex + 1.f)) * w2v[nt];
      }
      sum += __shfl_xor(sum, 1);
      sum += __shfl_xor(sum, 2);
      sum += __shfl_xor(sum, 4);
      sum += __shfl_xor(sum, 8);
      if (lrow == 0) ep[wn][wm * 64 + mt * 16 + kq * 4 + r] = sum;
    }
  }
  __syncthreads();
  if (tid < 128)
    epart[(size_t)nb * M_TOT + r0 + tid] = ep[0][tid] + ep[1][tid];
}

// ---------------------------------------------------------------------------
// Kernel 3: softmax over S per batch (8 epart planes, both paths).
// ---------------------------------------------------------------------------
__global__ __launch_bounds__(256) void softmax_kernel(
    const float* __restrict__ epart, float* __restrict__ alpha)
{
  int b = blockIdx.x, t = threadIdx.x;
  __shared__ float redmax[4], redsum[4];
  float ev[8];
  float lmax = -1e30f;
#pragma unroll
  for (int j = 0; j < 8; ++j) {
    int s = t + j * 256;
    float sum = 0.f;
#pragma unroll
    for (int p = 0; p < 8; ++p) sum += epart[(size_t)p * M_TOT + b * SEQ + s];
    ev[j] = sum;
    lmax = fmaxf(lmax, sum);
  }
#pragma unroll
  for (int msk = 1; msk < 64; msk <<= 1) lmax = fmaxf(lmax, __shfl_xor(lmax, msk));
  if ((t & 63) == 0) redmax[t >> 6] = lmax;
  __syncthreads();
  float bmax = fmaxf(fmaxf(redmax[0], redmax[1]), fmaxf(redmax[2], redmax[3]));
  float lsum = 0.f;
#pragma unroll
  for (int j = 0; j < 8; ++j) { ev[j] = __expf(ev[j] - bmax); lsum += ev[j]; }
#pragma unroll
  for (int msk = 1; msk < 64; msk <<= 1) lsum += __shfl_xor(lsum, msk);
  if ((t & 63) == 0) redsum[t >> 6] = lsum;
  __syncthreads();
  float inv = 1.f / (redsum[0] + redsum[1] + redsum[2] + redsum[3]);
#pragma unroll
  for (int j = 0; j < 8; ++j) alpha[b * SEQ + t + j * 256] = ev[j] * inv;
}

// ---------------------------------------------------------------------------
// Kernel 4 (primary): context from fp32 enc, atomic-free. grid (64,8) x 512.
// ---------------------------------------------------------------------------
__global__ __launch_bounds__(512) void context_f32_kernel(
    const float* __restrict__ enc, const float* __restrict__ alpha,
    float* __restrict__ out)
{
  __shared__ float red[16][128];
  int b = blockIdx.x, kc = blockIdx.y, t = threadIdx.x;
  int kl = (t & 31) * 4;              // k-local 0..124
  int strip = t >> 5;                 // 0..15
  const float* ep = enc + ((size_t)b * SEQ + strip * 128) * 1024 + kc * 128 + kl;
  const float* ap = alpha + b * SEQ + strip * 128;
  float a0 = 0.f, a1 = 0.f, a2 = 0.f, a3 = 0.f;
#pragma unroll 4
  for (int s = 0; s < 128; ++s) {
    float a = ap[s];
    float4 v = *(const float4*)(ep + (size_t)s * 1024);
    a0 += a * v.x; a1 += a * v.y; a2 += a * v.z; a3 += a * v.w;
  }
  red[strip][kl + 0] = a0;
  red[strip][kl + 1] = a1;
  red[strip][kl + 2] = a2;
  red[strip][kl + 3] = a3;
  __syncthreads();
  if (t < 128) {
    float s = 0.f;
#pragma unroll
    for (int j = 0; j < 16; ++j) s += red[j][t];
    out[b * 1024 + kc * 128 + t] = s;
  }
}

// ---------------------------------------------------------------------------
// Kernel 4 (fallback): fp32 context with atomics.
// ---------------------------------------------------------------------------
__global__ __launch_bounds__(256) void context_kernel(
    const float* __restrict__ enc, const float* __restrict__ alpha,
    float* __restrict__ out)
{
  int b = blockIdx.y, sq = blockIdx.z, t = threadIdx.x;
  int k4 = t * 4;
  const float* ep = enc + ((size_t)b * SEQ + sq * 128) * 1024 + k4;
  const float* ap = alpha + b * SEQ + sq * 128;
  float ax = 0.f, ay = 0.f, az = 0.f, aw = 0.f;
#pragma unroll 4
  for (int s = 0; s < 128; ++s) {
    float a = ap[s];
    float4 v = *(const float4*)(ep + (size_t)s * 1024);
    ax += a * v.x; ay += a * v.y; az += a * v.z; aw += a * v.w;
  }
  float* o = out + b * 1024 + k4;
  atomicAdd(o + 0, ax);
  atomicAdd(o + 1, ay);
  atomicAdd(o + 2, az);
  atomicAdd(o + 3, aw);
}

// ---------------------------------------------------------------------------
extern "C" void kernel_launch(void* const* d_in, const int* in_sizes, int n_in,
                              void* d_out, int out_size, void* d_ws, size_t ws_size,
                              hipStream_t stream) {
  const float* hid = (const float*)d_in[0];
  const float* enc = (const float*)d_in[1];
  const float* W1  = (const float*)d_in[2];
  const float* b1  = (const float*)d_in[3];
  const float* W2  = (const float*)d_in[4];
  float* out = (float*)d_out;

  float* epart = (float*)d_ws;                       // NB * M_TOT planes
  float* alpha = epart + (size_t)NB * M_TOT;         // M_TOT
  float* hvec  = alpha + M_TOT;                      // 64*1024
  size_t small_bytes = ((size_t)NB * M_TOT + M_TOT + 64 * 1024) * 4;
  size_t encB_off = ((small_bytes + 255) / 256) * 256;
  size_t need = encB_off + (size_t)M_TOT * 1024 * 2 + (size_t)1024 * 1024 * 2;

  hvec_kernel<<<dim3(64, 64), 256, 0, stream>>>(hid, W1, b1, hvec);

  if (ws_size >= need) {
    unsigned short* encB = (unsigned short*)((char*)d_ws + encB_off);
    unsigned short* W1eB = encB + (size_t)M_TOT * 1024;
    convert_enc_frag_kernel<<<65536, 256, 0, stream>>>(enc, (unsigned int*)encB);
    convert_w1e_frag_kernel<<<512, 256, 0, stream>>>(W1, (unsigned int*)W1eB);
    gemm256x128_kernel<<<4096, 512, 0, stream>>>(encB, W1eB, W2, hvec, epart);
    softmax_kernel<<<64, 256, 0, stream>>>(epart, alpha);
    context_f32_kernel<<<dim3(64, 8), 512, 0, stream>>>(enc, alpha, out);
  } else {
    hipMemsetAsync(d_out, 0, (size_t)out_size * sizeof(float), stream);
    fused_gemm_kernel<<<dim3(NB, 1024), 256, 0, stream>>>(enc, W1, W2, hvec, epart);
    softmax_kernel<<<64, 256, 0, stream>>>(epart, alpha);
    context_kernel<<<dim3(1, 64, 16), 256, 0, stream>>>(enc, alpha, out);
  }
}

// Round 7
// 1088.428 us; speedup vs baseline: 1.0617x; 1.0450x over previous
//
#include <hip/hip_runtime.h>

typedef __attribute__((ext_vector_type(8))) short short8;
typedef __attribute__((ext_vector_type(4))) float floatx4;

#define M_TOT 131072   // B*S = 64*2048
#define SEQ   2048
#define NB    8        // n-tiles (1024/128), both paths

__device__ __forceinline__ unsigned bf16rne(float x) {
  unsigned u = __float_as_uint(x);
  return (u + 0x7FFFu + ((u >> 16) & 1u)) >> 16;
}

#define GLOAD_LDS16(g, l) __builtin_amdgcn_global_load_lds( \
    (const __attribute__((address_space(1))) unsigned int*)(g), \
    (__attribute__((address_space(3))) unsigned int*)(l), 16, 0, 0)

// ---------------------------------------------------------------------------
// Convert enc fp32 -> bf16 in MFMA-FRAGMENT ORDER for the 256x128 GEMM.
// Chunk C = (mb*32 + t)*1024 + c; c = (wm*4 + mt)*64 + l  (16B chunks).
// Element e of chunk: row = mb*256 + wm*64 + mt*16 + (l&15),
//                     k   = t*32 + (l>>4)*8 + e.
// Equivalently C = mb*32768 + t*1024 + wm*256 + mt*64 + (l>>4)*16 + (l&15).
// GEMM stages chunks linearly with gload_lds -> LDS holds frag order ->
// every fragment ds_read_b128 is lane-linear (zero bank conflicts).
// ---------------------------------------------------------------------------
__global__ __launch_bounds__(256) void convert_enc_frag_kernel(
    const float* __restrict__ in, unsigned int* __restrict__ out)
{
  unsigned C = blockIdx.x * 256 + threadIdx.x;     // 0..16777215
  int l = C & 63, mt = (C >> 6) & 3, wm = (C >> 8) & 3;
  int t = (C >> 10) & 31, mb = C >> 15;
  int row = mb * 256 + wm * 64 + mt * 16 + (l & 15);
  int k0  = t * 32 + (l >> 4) * 8;
  const float* p = in + (size_t)row * 1024 + k0;
  float4 a = *(const float4*)p;
  float4 b = *(const float4*)(p + 4);
  uint4 o;
  o.x = bf16rne(a.x) | (bf16rne(a.y) << 16);
  o.y = bf16rne(a.z) | (bf16rne(a.w) << 16);
  o.z = bf16rne(b.x) | (bf16rne(b.y) << 16);
  o.w = bf16rne(b.z) | (bf16rne(b.w) << 16);
  *(uint4*)(out + (size_t)C * 4) = o;
}

// ---------------------------------------------------------------------------
// Convert W1e fp32 -> bf16 in MFMA-FRAGMENT ORDER.
// Chunk G = (nb*32 + t)*512 + c; c = (wn*4 + nt)*64 + l.
// d = nb*128 + wn*64 + nt*16 + (l&15); k = t*32 + (l>>4)*8 + e.
// ---------------------------------------------------------------------------
__global__ __launch_bounds__(256) void convert_w1e_frag_kernel(
    const float* __restrict__ W1, unsigned int* __restrict__ out)
{
  unsigned G = blockIdx.x * 256 + threadIdx.x;     // 0..131071
  int l = G & 63, nt = (G >> 6) & 3, wn = (G >> 8) & 1;
  int t = (G >> 9) & 31, nb = G >> 14;
  int d  = nb * 128 + wn * 64 + nt * 16 + (l & 15);
  int k0 = t * 32 + (l >> 4) * 8;
  const float* p = W1 + (size_t)d * 2048 + k0;
  float4 a = *(const float4*)p;
  float4 b = *(const float4*)(p + 4);
  uint4 o;
  o.x = bf16rne(a.x) | (bf16rne(a.y) << 16);
  o.y = bf16rne(a.z) | (bf16rne(a.w) << 16);
  o.z = bf16rne(b.x) | (bf16rne(b.y) << 16);
  o.w = bf16rne(b.z) | (bf16rne(b.w) << 16);
  *(uint4*)(out + (size_t)G * 4) = o;
}

// ---------------------------------------------------------------------------
// Kernel 1: hvec[b,d] = b1[d] + sum_m hid[b,m] * W1[d, 1024+m]
// ---------------------------------------------------------------------------
__global__ __launch_bounds__(256) void hvec_kernel(
    const float* __restrict__ hid, const float* __restrict__ W1,
    const float* __restrict__ b1, float* __restrict__ hvec)
{
  int b = blockIdx.x, g = blockIdx.y;
  int w = threadIdx.x >> 6, lane = threadIdx.x & 63;
  const float* hrow = hid + b * 1024;
  for (int i = 0; i < 4; ++i) {
    int d = g * 16 + w * 4 + i;
    const float* wrow = W1 + (size_t)d * 2048 + 1024;
    float sum = 0.f;
#pragma unroll
    for (int c = 0; c < 4; ++c) {
      int m = c * 256 + lane * 4;
      float4 wv = *(const float4*)(wrow + m);
      float4 hv = *(const float4*)(hrow + m);
      sum += wv.x * hv.x + wv.y * hv.y + wv.z * hv.z + wv.w * hv.w;
    }
#pragma unroll
    for (int msk = 1; msk < 64; msk <<= 1) sum += __shfl_xor(sum, msk);
    if (lane == 0) hvec[b * 1024 + d] = sum + b1[d];
  }
}

// ---------------------------------------------------------------------------
// Kernel 2 (primary): 256x128 tile, BK=32, 8 waves (4M x 2N, 64x64/wave),
// 2 BLOCKS/CU (LDS 72 KB, <=128 VGPR via __launch_bounds__(512,4)).
// Ring-3 slots, counted vmcnt(3) (1-tile lead), one barrier/tile.
// Frag-order layout -> all ds_read_b128 lane-linear, 0 conflicts.
// (Measured R6: ~325-330 us, below the 330 us fill dispatches -- the
//  m97-structure plateau. Do not perturb this round.)
// ---------------------------------------------------------------------------
__global__ __launch_bounds__(512, 4) void gemm256x128_kernel(
    const unsigned short* __restrict__ encB, const unsigned short* __restrict__ W1eB,
    const float* __restrict__ W2, const float* __restrict__ hvec,
    float* __restrict__ epart)
{
  __shared__ __align__(16) unsigned short ldsA[3][8192];   // 48 KB (3 x 256x32)
  __shared__ __align__(16) unsigned short ldsB[3][4096];   // 24 KB (3 x 128x32)

  const int tid = threadIdx.x;
  const int lid = blockIdx.x;            // 0..4095
  const int xcd = lid & 7, q = lid >> 3; // bijective XCD swizzle (4096%8==0)
  const int mb = xcd * 64 + (q >> 3);    // 0..511
  const int nb = q & 7;                  // 0..7
  const int r0 = mb * 256;
  const int bidx = mb >> 3;              // batch (256 divides S=2048)
  const int wid = tid >> 6, lane = tid & 63;
  const int wm = wid >> 1, wn = wid & 1; // 4M x 2N waves, per-wave 64x64
  const int lrow = lane & 15, kq = lane >> 4;
  const int lane8 = lane * 8;

  floatx4 acc[4][4];
#pragma unroll
  for (int i = 0; i < 4; ++i)
#pragma unroll
    for (int j = 0; j < 4; ++j)
      acc[i][j] = (floatx4){0.f, 0.f, 0.f, 0.f};

  unsigned short *aCur = ldsA[0], *aNx = ldsA[1], *aN2 = ldsA[2];
  unsigned short *bCur = ldsB[0], *bNx = ldsB[1], *bN2 = ldsB[2];

  // prologue: stage tile 0 (3 gloads/thread) into slot 0
  {
    const unsigned short* ga = encB + ((size_t)mb * 32 * 1024 + tid) * 8;
    GLOAD_LDS16(ga,        &aCur[wid * 512]);
    GLOAD_LDS16(ga + 4096, &aCur[4096 + wid * 512]);
    const unsigned short* gb = W1eB + ((size_t)nb * 32 * 512 + tid) * 8;
    GLOAD_LDS16(gb,        &bCur[wid * 512]);
  }

  const int aRd = wm * 2048 + lane8;   // + mt*512
  const int bRd = wn * 2048 + lane8;   // + nt*512

  for (int t = 0; t < 32; ++t) {
    if (t < 31) {
      const unsigned short* ga = encB + ((size_t)(mb * 32 + t + 1) * 1024 + tid) * 8;
      GLOAD_LDS16(ga,        &aNx[wid * 512]);
      GLOAD_LDS16(ga + 4096, &aNx[4096 + wid * 512]);
      const unsigned short* gb = W1eB + ((size_t)(nb * 32 + t + 1) * 512 + tid) * 8;
      GLOAD_LDS16(gb,        &bNx[wid * 512]);
      asm volatile("s_waitcnt vmcnt(3)" ::: "memory");   // tile t landed
    } else {
      asm volatile("s_waitcnt vmcnt(0)" ::: "memory");
    }
    __builtin_amdgcn_s_barrier();                        // publish tile t

    short8 af[4], bf[4];
#pragma unroll
    for (int mt = 0; mt < 4; ++mt) af[mt] = *(const short8*)&aCur[aRd + mt * 512];
#pragma unroll
    for (int nt = 0; nt < 4; ++nt) bf[nt] = *(const short8*)&bCur[bRd + nt * 512];
    __builtin_amdgcn_s_setprio(1);
#pragma unroll
    for (int mt = 0; mt < 4; ++mt)
#pragma unroll
      for (int nt = 0; nt < 4; ++nt)
        acc[mt][nt] = __builtin_amdgcn_mfma_f32_16x16x32_bf16(
            af[mt], bf[nt], acc[mt][nt], 0, 0, 0);
    __builtin_amdgcn_s_setprio(0);

    unsigned short* tA = aCur; aCur = aNx; aNx = aN2; aN2 = tA;
    unsigned short* tB = bCur; bCur = bNx; bNx = bN2; bN2 = tB;
  }

  // epilogue: tanh + W2-dot -> epart plane nb. All DMA drained (vmcnt(0)).
  __syncthreads();
  float* ep = (float*)&ldsA[0][0];   // [2 wn][256 m] floats (2 KB)
  float hv[4], w2v[4];
#pragma unroll
  for (int nt = 0; nt < 4; ++nt) {
    int n = nb * 128 + wn * 64 + nt * 16 + lrow;
    hv[nt]  = hvec[bidx * 1024 + n];
    w2v[nt] = W2[n];
  }
#pragma unroll
  for (int mt = 0; mt < 4; ++mt) {
#pragma unroll
    for (int r = 0; r < 4; ++r) {
      float sum = 0.f;
#pragma unroll
      for (int nt = 0; nt < 4; ++nt) {
        float pre = acc[mt][nt][r] + hv[nt];
        float ex = __expf(2.f * pre);
        sum += (1.f - 2.f / (ex + 1.f)) * w2v[nt];
      }
      sum += __shfl_xor(sum, 1);
      sum += __shfl_xor(sum, 2);
      sum += __shfl_xor(sum, 4);
      sum += __shfl_xor(sum, 8);
      if (lrow == 0) ep[wn * 256 + wm * 64 + mt * 16 + kq * 4 + r] = sum;
    }
  }
  __syncthreads();
  if (tid < 256)
    epart[(size_t)nb * M_TOT + r0 + tid] = ep[tid] + ep[256 + tid];
}

// ---------------------------------------------------------------------------
// Kernel 2 (fallback, no-ws path): fused GEMM with in-loop convert (128-tile).
// ---------------------------------------------------------------------------
__global__ __launch_bounds__(256) void fused_gemm_kernel(
    const float* __restrict__ enc, const float* __restrict__ W1,
    const float* __restrict__ W2, const float* __restrict__ hvec,
    float* __restrict__ epart)
{
  __shared__ __align__(16) unsigned short Ah[128 * 32];
  __shared__ __align__(16) unsigned short Bh[128 * 32];
  __shared__ float ep[2][128];

  const int tid = threadIdx.x;
  const int nb = blockIdx.x, mb = blockIdx.y;
  const int r0 = mb * 128, n0 = nb * 128;
  const int bidx = r0 >> 11;
  const int w = tid >> 6, lane = tid & 63;
  const int wm = w >> 1, wn = w & 1;
  const int lrow = lane & 15, kq = lane >> 4;

  floatx4 acc[4][4];
#pragma unroll
  for (int i = 0; i < 4; ++i)
#pragma unroll
    for (int j = 0; j < 4; ++j)
      acc[i][j] = (floatx4){0.f, 0.f, 0.f, 0.f};

  const int srow = tid >> 3;
  const int scol = (tid & 7) * 4;
  const float* aptr = enc + (size_t)(r0 + srow) * 1024 + scol;
  const float* bptr = W1  + (size_t)(n0 + srow) * 2048 + scol;

  for (int k0 = 0; k0 < 1024; k0 += 32) {
    float4 av[4], bv[4];
#pragma unroll
    for (int j = 0; j < 4; ++j) {
      av[j] = *(const float4*)(aptr + (size_t)(j * 32) * 1024 + k0);
      bv[j] = *(const float4*)(bptr + (size_t)(j * 32) * 2048 + k0);
    }
    __syncthreads();
#pragma unroll
    for (int j = 0; j < 4; ++j) {
      unsigned ax = __float_as_uint(av[j].x), ay = __float_as_uint(av[j].y);
      unsigned az = __float_as_uint(av[j].z), aw = __float_as_uint(av[j].w);
      unsigned a01 = __builtin_amdgcn_perm(ay, ax, 0x07060302u);
      unsigned a23 = __builtin_amdgcn_perm(aw, az, 0x07060302u);
      *(uint2*)&Ah[(tid + j * 256) * 4] = make_uint2(a01, a23);
      unsigned bx = __float_as_uint(bv[j].x), by = __float_as_uint(bv[j].y);
      unsigned bz = __float_as_uint(bv[j].z), bw = __float_as_uint(bv[j].w);
      unsigned b01 = __builtin_amdgcn_perm(by, bx, 0x07060302u);
      unsigned b23 = __builtin_amdgcn_perm(bw, bz, 0x07060302u);
      *(uint2*)&Bh[(tid + j * 256) * 4] = make_uint2(b01, b23);
    }
    __syncthreads();

    short8 af[4], bfm[4];
#pragma unroll
    for (int t4 = 0; t4 < 4; ++t4) {
      af[t4]  = *(const short8*)&Ah[(wm * 64 + t4 * 16 + lrow) * 32 + kq * 8];
      bfm[t4] = *(const short8*)&Bh[(wn * 64 + t4 * 16 + lrow) * 32 + kq * 8];
    }
#pragma unroll
    for (int mt = 0; mt < 4; ++mt)
#pragma unroll
      for (int nt = 0; nt < 4; ++nt)
        acc[mt][nt] = __builtin_amdgcn_mfma_f32_16x16x32_bf16(
            af[mt], bfm[nt], acc[mt][nt], 0, 0, 0);
  }

  float hv[4], w2v[4];
#pragma unroll
  for (int nt = 0; nt < 4; ++nt) {
    int n = n0 + wn * 64 + nt * 16 + lrow;
    hv[nt]  = hvec[bidx * 1024 + n];
    w2v[nt] = W2[n];
  }
#pragma unroll
  for (int mt = 0; mt < 4; ++mt) {
#pragma unroll
    for (int r = 0; r < 4; ++r) {
      float sum = 0.f;
#pragma unroll
      for (int nt = 0; nt < 4; ++nt) {
        float pre = acc[mt][nt][r] + hv[nt];
        float ex = __expf(2.f * pre);
        sum += (1.f - 2.f / (ex + 1.f)) * w2v[nt];
      }
      sum += __shfl_xor(sum, 1);
      sum += __shfl_xor(sum, 2);
      sum += __shfl_xor(sum, 4);
      sum += __shfl_xor(sum, 8);
      if (lrow == 0) ep[wn][wm * 64 + mt * 16 + kq * 4 + r] = sum;
    }
  }
  __syncthreads();
  if (tid < 128)
    epart[(size_t)nb * M_TOT + r0 + tid] = ep[0][tid] + ep[1][tid];
}

// ---------------------------------------------------------------------------
// Kernel 3: softmax over S per batch (8 epart planes, both paths).
// ---------------------------------------------------------------------------
__global__ __launch_bounds__(256) void softmax_kernel(
    const float* __restrict__ epart, float* __restrict__ alpha)
{
  int b = blockIdx.x, t = threadIdx.x;
  __shared__ float redmax[4], redsum[4];
  float ev[8];
  float lmax = -1e30f;
#pragma unroll
  for (int j = 0; j < 8; ++j) {
    int s = t + j * 256;
    float sum = 0.f;
#pragma unroll
    for (int p = 0; p < 8; ++p) sum += epart[(size_t)p * M_TOT + b * SEQ + s];
    ev[j] = sum;
    lmax = fmaxf(lmax, sum);
  }
#pragma unroll
  for (int msk = 1; msk < 64; msk <<= 1) lmax = fmaxf(lmax, __shfl_xor(lmax, msk));
  if ((t & 63) == 0) redmax[t >> 6] = lmax;
  __syncthreads();
  float bmax = fmaxf(fmaxf(redmax[0], redmax[1]), fmaxf(redmax[2], redmax[3]));
  float lsum = 0.f;
#pragma unroll
  for (int j = 0; j < 8; ++j) { ev[j] = __expf(ev[j] - bmax); lsum += ev[j]; }
#pragma unroll
  for (int msk = 1; msk < 64; msk <<= 1) lsum += __shfl_xor(lsum, msk);
  if ((t & 63) == 0) redsum[t >> 6] = lsum;
  __syncthreads();
  float inv = 1.f / (redsum[0] + redsum[1] + redsum[2] + redsum[3]);
#pragma unroll
  for (int j = 0; j < 8; ++j) alpha[b * SEQ + t + j * 256] = ev[j] * inv;
}

// ---------------------------------------------------------------------------
// Kernel 4 (primary): context from FRAG-ORDER bf16 encB (halves the traffic
// vs fp32 enc: 268 MB vs 537 MB). Exact mirror of convert_enc_frag mapping:
//   C = mb*32768 + t*1024 + wm*256 + mt*64 + kq3*16 + lr,
//   row = mb*256 + wm*64 + mt*16 + lr, k = t*32 + kq3*8 + e.
// Block (b, kc): 256 thr = 16 k-octets x 16 s-strips of 128 rows.
// Lane owns one 16B chunk/row; consecutive rows in a 16-group -> consecutive
// chunks (256B streams). LDS reduce over strips; single coalesced write.
// ---------------------------------------------------------------------------
__global__ __launch_bounds__(256) void context_encB_kernel(
    const unsigned int* __restrict__ encB, const float* __restrict__ alpha,
    float* __restrict__ out)
{
  __shared__ float red[16][16][8];   // [strip][octet][e] = 8 KB
  const int b = blockIdx.x, kc = blockIdx.y, tid = threadIdx.x;
  const int o = tid & 15;            // octet: t-offset = o>>2, kq3 = o&3
  const int strip = tid >> 4;        // 0..15, rows strip*128 .. +127
  const uint4* e4 = (const uint4*)encB;

  // Cbase for sl = 0 (see mapping above); mb = b*8 + strip/2, wm-high = strip&1
  const size_t Cbase = (size_t)(b * 8 + (strip >> 1)) * 32768
                     + (size_t)(kc * 4 + (o >> 2)) * 1024
                     + (strip & 1) * 512 + (o & 3) * 16;
  const float* ap = alpha + b * SEQ + strip * 128;

  float acc0 = 0.f, acc1 = 0.f, acc2 = 0.f, acc3 = 0.f;
  float acc4 = 0.f, acc5 = 0.f, acc6 = 0.f, acc7 = 0.f;
#pragma unroll 4
  for (int sl = 0; sl < 128; ++sl) {
    size_t C = Cbase + ((sl >> 6) << 8) + (((sl >> 4) & 3) << 6) + (sl & 15);
    uint4 v = e4[C];
    float a = ap[sl];
    acc0 += a * __uint_as_float(v.x << 16);
    acc1 += a * __uint_as_float(v.x & 0xFFFF0000u);
    acc2 += a * __uint_as_float(v.y << 16);
    acc3 += a * __uint_as_float(v.y & 0xFFFF0000u);
    acc4 += a * __uint_as_float(v.z << 16);
    acc5 += a * __uint_as_float(v.z & 0xFFFF0000u);
    acc6 += a * __uint_as_float(v.w << 16);
    acc7 += a * __uint_as_float(v.w & 0xFFFF0000u);
  }
  red[strip][o][0] = acc0; red[strip][o][1] = acc1;
  red[strip][o][2] = acc2; red[strip][o][3] = acc3;
  red[strip][o][4] = acc4; red[strip][o][5] = acc5;
  red[strip][o][6] = acc6; red[strip][o][7] = acc7;
  __syncthreads();
  if (tid < 128) {
    // klocal = tid = to*32 + kq3*8 + e  ->  octet = to*4 + kq3
    int to = tid >> 5, kq3 = (tid >> 3) & 3, e = tid & 7;
    int oc = to * 4 + kq3;
    float s = 0.f;
#pragma unroll
    for (int j = 0; j < 16; ++j) s += red[j][oc][e];
    out[b * 1024 + kc * 128 + tid] = s;
  }
}

// ---------------------------------------------------------------------------
// Kernel 4 (fallback): fp32 context with atomics.
// ---------------------------------------------------------------------------
__global__ __launch_bounds__(256) void context_kernel(
    const float* __restrict__ enc, const float* __restrict__ alpha,
    float* __restrict__ out)
{
  int b = blockIdx.y, sq = blockIdx.z, t = threadIdx.x;
  int k4 = t * 4;
  const float* ep = enc + ((size_t)b * SEQ + sq * 128) * 1024 + k4;
  const float* ap = alpha + b * SEQ + sq * 128;
  float ax = 0.f, ay = 0.f, az = 0.f, aw = 0.f;
#pragma unroll 4
  for (int s = 0; s < 128; ++s) {
    float a = ap[s];
    float4 v = *(const float4*)(ep + (size_t)s * 1024);
    ax += a * v.x; ay += a * v.y; az += a * v.z; aw += a * v.w;
  }
  float* o = out + b * 1024 + k4;
  atomicAdd(o + 0, ax);
  atomicAdd(o + 1, ay);
  atomicAdd(o + 2, az);
  atomicAdd(o + 3, aw);
}

// ---------------------------------------------------------------------------
extern "C" void kernel_launch(void* const* d_in, const int* in_sizes, int n_in,
                              void* d_out, int out_size, void* d_ws, size_t ws_size,
                              hipStream_t stream) {
  const float* hid = (const float*)d_in[0];
  const float* enc = (const float*)d_in[1];
  const float* W1  = (const float*)d_in[2];
  const float* b1  = (const float*)d_in[3];
  const float* W2  = (const float*)d_in[4];
  float* out = (float*)d_out;

  float* epart = (float*)d_ws;                       // NB * M_TOT planes
  float* alpha = epart + (size_t)NB * M_TOT;         // M_TOT
  float* hvec  = alpha + M_TOT;                      // 64*1024
  size_t small_bytes = ((size_t)NB * M_TOT + M_TOT + 64 * 1024) * 4;
  size_t encB_off = ((small_bytes + 255) / 256) * 256;
  size_t need = encB_off + (size_t)M_TOT * 1024 * 2 + (size_t)1024 * 1024 * 2;

  hvec_kernel<<<dim3(64, 64), 256, 0, stream>>>(hid, W1, b1, hvec);

  if (ws_size >= need) {
    unsigned short* encB = (unsigned short*)((char*)d_ws + encB_off);
    unsigned short* W1eB = encB + (size_t)M_TOT * 1024;
    convert_enc_frag_kernel<<<65536, 256, 0, stream>>>(enc, (unsigned int*)encB);
    convert_w1e_frag_kernel<<<512, 256, 0, stream>>>(W1, (unsigned int*)W1eB);
    gemm256x128_kernel<<<4096, 512, 0, stream>>>(encB, W1eB, W2, hvec, epart);
    softmax_kernel<<<64, 256, 0, stream>>>(epart, alpha);
    context_encB_kernel<<<dim3(64, 8), 256, 0, stream>>>((unsigned int*)encB, alpha, out);
  } else {
    hipMemsetAsync(d_out, 0, (size_t)out_size * sizeof(float), stream);
    fused_gemm_kernel<<<dim3(NB, 1024), 256, 0, stream>>>(enc, W1, W2, hvec, epart);
    softmax_kernel<<<64, 256, 0, stream>>>(epart, alpha);
    context_kernel<<<dim3(1, 64, 16), 256, 0, stream>>>(enc, alpha, out);
  }
}

// Round 8
// 1077.592 us; speedup vs baseline: 1.0723x; 1.0101x over previous
//
#include <hip/hip_runtime.h>

typedef __attribute__((ext_vector_type(8))) short short8;
typedef __attribute__((ext_vector_type(4))) float floatx4;

#define M_TOT 131072   // B*S = 64*2048
#define SEQ   2048
#define NB    8        // n-tiles (1024/128), both paths

__device__ __forceinline__ unsigned bf16rne(float x) {
  unsigned u = __float_as_uint(x);
  return (u + 0x7FFFu + ((u >> 16) & 1u)) >> 16;
}

__device__ __forceinline__ unsigned cvtpk_bf16(float lo, float hi) {
  unsigned r;
  asm("v_cvt_pk_bf16_f32 %0, %1, %2" : "=v"(r) : "v"(lo), "v"(hi));
  return r;
}

#define GLOAD_LDS16(g, l) __builtin_amdgcn_global_load_lds( \
    (const __attribute__((address_space(1))) unsigned int*)(g), \
    (__attribute__((address_space(3))) unsigned int*)(l), 16, 0, 0)

// ---------------------------------------------------------------------------
// Convert W1e fp32 -> bf16 in MFMA-FRAGMENT ORDER (2 MB, ~2 us).
// Chunk G = (nb*32 + t)*512 + c; c = (wn*4 + nt)*64 + l.
// d = nb*128 + wn*64 + nt*16 + (l&15); k = t*32 + (l>>4)*8 + e.
// ---------------------------------------------------------------------------
__global__ __launch_bounds__(256) void convert_w1e_frag_kernel(
    const float* __restrict__ W1, unsigned int* __restrict__ out)
{
  unsigned G = blockIdx.x * 256 + threadIdx.x;     // 0..131071
  int l = G & 63, nt = (G >> 6) & 3, wn = (G >> 8) & 1;
  int t = (G >> 9) & 31, nb = G >> 14;
  int d  = nb * 128 + wn * 64 + nt * 16 + (l & 15);
  int k0 = t * 32 + (l >> 4) * 8;
  const float* p = W1 + (size_t)d * 2048 + k0;
  float4 a = *(const float4*)p;
  float4 b = *(const float4*)(p + 4);
  uint4 o;
  o.x = bf16rne(a.x) | (bf16rne(a.y) << 16);
  o.y = bf16rne(a.z) | (bf16rne(a.w) << 16);
  o.z = bf16rne(b.x) | (bf16rne(b.y) << 16);
  o.w = bf16rne(b.z) | (bf16rne(b.w) << 16);
  *(uint4*)(out + (size_t)G * 4) = o;
}

// ---------------------------------------------------------------------------
// Kernel 1: hvec[b,d] = b1[d] + sum_m hid[b,m] * W1[d, 1024+m]
// ---------------------------------------------------------------------------
__global__ __launch_bounds__(256) void hvec_kernel(
    const float* __restrict__ hid, const float* __restrict__ W1,
    const float* __restrict__ b1, float* __restrict__ hvec)
{
  int b = blockIdx.x, g = blockIdx.y;
  int w = threadIdx.x >> 6, lane = threadIdx.x & 63;
  const float* hrow = hid + b * 1024;
  for (int i = 0; i < 4; ++i) {
    int d = g * 16 + w * 4 + i;
    const float* wrow = W1 + (size_t)d * 2048 + 1024;
    float sum = 0.f;
#pragma unroll
    for (int c = 0; c < 4; ++c) {
      int m = c * 256 + lane * 4;
      float4 wv = *(const float4*)(wrow + m);
      float4 hv = *(const float4*)(hrow + m);
      sum += wv.x * hv.x + wv.y * hv.y + wv.z * hv.z + wv.w * hv.w;
    }
#pragma unroll
    for (int msk = 1; msk < 64; msk <<= 1) sum += __shfl_xor(sum, msk);
    if (lane == 0) hvec[b * 1024 + d] = sum + b1[d];
  }
}

// ---------------------------------------------------------------------------
// Kernel 2 (primary): FUSED fp32->bf16 + GEMM. 256x128 tile, BK=32, 8 waves
// (4M x 2N, 64x64/wave), 2 blocks/CU (LDS 72 KB, <=128 VGPR).
// A: fp32 enc -> regs (aR, issued at body t for tile t+2: FULL K-step latency
//    cover, fixing R4's one-phase stall) -> cvt_pk_bf16 -> ds_write_b128 into
//    frag-order LDS ring-3 (write pattern = 8 lanes/bank-quad = b128 floor,
//    conflict-free; read path identical to R6's proven kernel).
// B: pre-converted frag-order W1eB via gload_lds, ring-3, 1-body lead (R6).
// vmcnt ledger (in-order retirement): body t queue before wait =
//   [B(t), aR(t+2) x4, B(t+1)] -> vmcnt(5) retires B(t) (t<30);
//   t=30: [B(30), B(31)] -> vmcnt(1); t=31: vmcnt(0).
// Compiler auto-waits cover aR use (aR(t+1) issued BEFORE B(t) at body t-1,
// so its wait leaves B(t) in flight). One barrier per body.
// Ring-3 slot safety (both A and B): slot (t+1)%3 last read at body t-2,
// separated from body-t writes by barrier(t-1)  -- R6 discipline.
// ---------------------------------------------------------------------------
__global__ __launch_bounds__(512, 4) void gemm_fused_kernel(
    const float* __restrict__ enc, const unsigned short* __restrict__ W1eB,
    const float* __restrict__ W2, const float* __restrict__ hvec,
    float* __restrict__ epart)
{
  __shared__ __align__(16) unsigned short ldsA[3][8192];   // 48 KB (3 x 256x32)
  __shared__ __align__(16) unsigned short ldsB[3][4096];   // 24 KB (3 x 128x32)

  const int tid = threadIdx.x;
  const int lid = blockIdx.x;            // 0..4095
  const int xcd = lid & 7, q = lid >> 3; // bijective XCD swizzle (4096%8==0)
  const int mb = xcd * 64 + (q >> 3);    // 0..511
  const int nb = q & 7;                  // 0..7
  const int r0 = mb * 256;
  const int bidx = mb >> 3;              // batch (256 divides S=2048)
  const int wid = tid >> 6, lane = tid & 63;
  const int wm = wid >> 1, wn = wid & 1; // 4M x 2N waves, per-wave 64x64
  const int lrow = lane & 15, kq = lane >> 4;
  const int lane8 = lane * 8;

  // A staging map: c = tid + j*512 -> row = c>>2 (0..255), kc = c&3.
  // fp32 src: enc[(r0+row)*1024 + t*32 + kc*8 .. +8]  (128B/row segments)
  // frag-order dest chunk = (row>>4)*64 + (row&15) + kc*16 (16B chunks);
  // per-wave bank-quad = (l>>2)&7 -> exactly 8 lanes/quad (conflict-free).
  const float* aSrc[2];
  int aDst[2];
#pragma unroll
  for (int j = 0; j < 2; ++j) {
    int c = tid + j * 512, row = c >> 2, kc = c & 3;
    aSrc[j] = enc + (size_t)(r0 + row) * 1024 + kc * 8;
    aDst[j] = ((row >> 4) * 64 + (row & 15) + kc * 16) * 8;  // shorts
  }

  floatx4 acc[4][4];
#pragma unroll
  for (int i = 0; i < 4; ++i)
#pragma unroll
    for (int j = 0; j < 4; ++j)
      acc[i][j] = (floatx4){0.f, 0.f, 0.f, 0.f};

  float4 aR[2][2];
#define LOAD_AR(T) do { \
    _Pragma("unroll") \
    for (int j = 0; j < 2; ++j) { \
      aR[j][0] = *(const float4*)(aSrc[j] + (T) * 32); \
      aR[j][1] = *(const float4*)(aSrc[j] + (T) * 32 + 4); \
    } \
  } while (0)
#define CVT_WRITE_A(SL) do { \
    _Pragma("unroll") \
    for (int j = 0; j < 2; ++j) { \
      uint4 o; \
      o.x = cvtpk_bf16(aR[j][0].x, aR[j][0].y); \
      o.y = cvtpk_bf16(aR[j][0].z, aR[j][0].w); \
      o.z = cvtpk_bf16(aR[j][1].x, aR[j][1].y); \
      o.w = cvtpk_bf16(aR[j][1].z, aR[j][1].w); \
      *(uint4*)&ldsA[SL][aDst[j]] = o; \
    } \
  } while (0)
#define STAGE_B(T, SL) \
    GLOAD_LDS16(W1eB + ((size_t)(nb * 32 + (T)) * 512 + tid) * 8, \
                &ldsB[SL][wid * 512])

  // ---- prologue ----
  LOAD_AR(0);                    // aR(0)
  STAGE_B(0, 0);                 // B(0) DMA
  CVT_WRITE_A(0);                // A(0) -> slot 0 (auto-waits aR(0))
  LOAD_AR(1);                    // aR(1)

  const int aRd = wm * 2048 + lane8;   // + mt*512
  const int bRd = wn * 2048 + lane8;   // + nt*512

  int sCur = 0;
  for (int t = 0; t < 32; ++t) {
    const int sNx = (sCur == 2) ? 0 : sCur + 1;
    if (t < 31) {
      CVT_WRITE_A(sNx);                       // A(t+1), consumes aR(t+1)
      if (t < 30) LOAD_AR(t + 2);             // aR(t+2), 4 loads
      STAGE_B(t + 1, sNx);                    // B(t+1) DMA
      asm volatile("s_waitcnt lgkmcnt(0)" ::: "memory");   // A writes done
      if (t < 30) { asm volatile("s_waitcnt vmcnt(5)" ::: "memory"); }
      else        { asm volatile("s_waitcnt vmcnt(1)" ::: "memory"); }
    } else {
      asm volatile("s_waitcnt vmcnt(0) lgkmcnt(0)" ::: "memory");
    }
    __builtin_amdgcn_s_barrier();             // publish A(t+1)-writes, B(t)

    short8 af[4], bf[4];
#pragma unroll
    for (int mt = 0; mt < 4; ++mt)
      af[mt] = *(const short8*)&ldsA[sCur][aRd + mt * 512];
#pragma unroll
    for (int nt = 0; nt < 4; ++nt)
      bf[nt] = *(const short8*)&ldsB[sCur][bRd + nt * 512];
    __builtin_amdgcn_s_setprio(1);
#pragma unroll
    for (int mt = 0; mt < 4; ++mt)
#pragma unroll
      for (int nt = 0; nt < 4; ++nt)
        acc[mt][nt] = __builtin_amdgcn_mfma_f32_16x16x32_bf16(
            af[mt], bf[nt], acc[mt][nt], 0, 0, 0);
    __builtin_amdgcn_s_setprio(0);

    sCur = sNx;
  }
#undef LOAD_AR
#undef CVT_WRITE_A
#undef STAGE_B

  // epilogue: tanh + W2-dot -> epart plane nb. All DMA drained (vmcnt(0)).
  __syncthreads();
  float* ep = (float*)&ldsA[0][0];   // [2 wn][256 m] floats (2 KB)
  float hv[4], w2v[4];
#pragma unroll
  for (int nt = 0; nt < 4; ++nt) {
    int n = nb * 128 + wn * 64 + nt * 16 + lrow;
    hv[nt]  = hvec[bidx * 1024 + n];
    w2v[nt] = W2[n];
  }
#pragma unroll
  for (int mt = 0; mt < 4; ++mt) {
#pragma unroll
    for (int r = 0; r < 4; ++r) {
      float sum = 0.f;
#pragma unroll
      for (int nt = 0; nt < 4; ++nt) {
        float pre = acc[mt][nt][r] + hv[nt];
        float ex = __expf(2.f * pre);
        sum += (1.f - 2.f / (ex + 1.f)) * w2v[nt];
      }
      sum += __shfl_xor(sum, 1);
      sum += __shfl_xor(sum, 2);
      sum += __shfl_xor(sum, 4);
      sum += __shfl_xor(sum, 8);
      if (lrow == 0) ep[wn * 256 + wm * 64 + mt * 16 + kq * 4 + r] = sum;
    }
  }
  __syncthreads();
  if (tid < 256)
    epart[(size_t)nb * M_TOT + r0 + tid] = ep[tid] + ep[256 + tid];
}

// ---------------------------------------------------------------------------
// Kernel 2 (fallback, no-ws path): fused GEMM with in-loop convert (128-tile).
// ---------------------------------------------------------------------------
__global__ __launch_bounds__(256) void fused_gemm_kernel(
    const float* __restrict__ enc, const float* __restrict__ W1,
    const float* __restrict__ W2, const float* __restrict__ hvec,
    float* __restrict__ epart)
{
  __shared__ __align__(16) unsigned short Ah[128 * 32];
  __shared__ __align__(16) unsigned short Bh[128 * 32];
  __shared__ float ep[2][128];

  const int tid = threadIdx.x;
  const int nb = blockIdx.x, mb = blockIdx.y;
  const int r0 = mb * 128, n0 = nb * 128;
  const int bidx = r0 >> 11;
  const int w = tid >> 6, lane = tid & 63;
  const int wm = w >> 1, wn = w & 1;
  const int lrow = lane & 15, kq = lane >> 4;

  floatx4 acc[4][4];
#pragma unroll
  for (int i = 0; i < 4; ++i)
#pragma unroll
    for (int j = 0; j < 4; ++j)
      acc[i][j] = (floatx4){0.f, 0.f, 0.f, 0.f};

  const int srow = tid >> 3;
  const int scol = (tid & 7) * 4;
  const float* aptr = enc + (size_t)(r0 + srow) * 1024 + scol;
  const float* bptr = W1  + (size_t)(n0 + srow) * 2048 + scol;

  for (int k0 = 0; k0 < 1024; k0 += 32) {
    float4 av[4], bv[4];
#pragma unroll
    for (int j = 0; j < 4; ++j) {
      av[j] = *(const float4*)(aptr + (size_t)(j * 32) * 1024 + k0);
      bv[j] = *(const float4*)(bptr + (size_t)(j * 32) * 2048 + k0);
    }
    __syncthreads();
#pragma unroll
    for (int j = 0; j < 4; ++j) {
      unsigned ax = __float_as_uint(av[j].x), ay = __float_as_uint(av[j].y);
      unsigned az = __float_as_uint(av[j].z), aw = __float_as_uint(av[j].w);
      unsigned a01 = __builtin_amdgcn_perm(ay, ax, 0x07060302u);
      unsigned a23 = __builtin_amdgcn_perm(aw, az, 0x07060302u);
      *(uint2*)&Ah[(tid + j * 256) * 4] = make_uint2(a01, a23);
      unsigned bx = __float_as_uint(bv[j].x), by = __float_as_uint(bv[j].y);
      unsigned bz = __float_as_uint(bv[j].z), bw = __float_as_uint(bv[j].w);
      unsigned b01 = __builtin_amdgcn_perm(by, bx, 0x07060302u);
      unsigned b23 = __builtin_amdgcn_perm(bw, bz, 0x07060302u);
      *(uint2*)&Bh[(tid + j * 256) * 4] = make_uint2(b01, b23);
    }
    __syncthreads();

    short8 af[4], bfm[4];
#pragma unroll
    for (int t4 = 0; t4 < 4; ++t4) {
      af[t4]  = *(const short8*)&Ah[(wm * 64 + t4 * 16 + lrow) * 32 + kq * 8];
      bfm[t4] = *(const short8*)&Bh[(wn * 64 + t4 * 16 + lrow) * 32 + kq * 8];
    }
#pragma unroll
    for (int mt = 0; mt < 4; ++mt)
#pragma unroll
      for (int nt = 0; nt < 4; ++nt)
        acc[mt][nt] = __builtin_amdgcn_mfma_f32_16x16x32_bf16(
            af[mt], bfm[nt], acc[mt][nt], 0, 0, 0);
  }

  float hv[4], w2v[4];
#pragma unroll
  for (int nt = 0; nt < 4; ++nt) {
    int n = n0 + wn * 64 + nt * 16 + lrow;
    hv[nt]  = hvec[bidx * 1024 + n];
    w2v[nt] = W2[n];
  }
#pragma unroll
  for (int mt = 0; mt < 4; ++mt) {
#pragma unroll
    for (int r = 0; r < 4; ++r) {
      float sum = 0.f;
#pragma unroll
      for (int nt = 0; nt < 4; ++nt) {
        float pre = acc[mt][nt][r] + hv[nt];
        float ex = __expf(2.f * pre);
        sum += (1.f - 2.f / (ex + 1.f)) * w2v[nt];
      }
      sum += __shfl_xor(sum, 1);
      sum += __shfl_xor(sum, 2);
      sum += __shfl_xor(sum, 4);
      sum += __shfl_xor(sum, 8);
      if (lrow == 0) ep[wn][wm * 64 + mt * 16 + kq * 4 + r] = sum;
    }
  }
  __syncthreads();
  if (tid < 128)
    epart[(size_t)nb * M_TOT + r0 + tid] = ep[0][tid] + ep[1][tid];
}

// ---------------------------------------------------------------------------
// Kernel 3: softmax over S per batch (8 epart planes, both paths).
// ---------------------------------------------------------------------------
__global__ __launch_bounds__(256) void softmax_kernel(
    const float* __restrict__ epart, float* __restrict__ alpha)
{
  int b = blockIdx.x, t = threadIdx.x;
  __shared__ float redmax[4], redsum[4];
  float ev[8];
  float lmax = -1e30f;
#pragma unroll
  for (int j = 0; j < 8; ++j) {
    int s = t + j * 256;
    float sum = 0.f;
#pragma unroll
    for (int p = 0; p < 8; ++p) sum += epart[(size_t)p * M_TOT + b * SEQ + s];
    ev[j] = sum;
    lmax = fmaxf(lmax, sum);
  }
#pragma unroll
  for (int msk = 1; msk < 64; msk <<= 1) lmax = fmaxf(lmax, __shfl_xor(lmax, msk));
  if ((t & 63) == 0) redmax[t >> 6] = lmax;
  __syncthreads();
  float bmax = fmaxf(fmaxf(redmax[0], redmax[1]), fmaxf(redmax[2], redmax[3]));
  float lsum = 0.f;
#pragma unroll
  for (int j = 0; j < 8; ++j) { ev[j] = __expf(ev[j] - bmax); lsum += ev[j]; }
#pragma unroll
  for (int msk = 1; msk < 64; msk <<= 1) lsum += __shfl_xor(lsum, msk);
  if ((t & 63) == 0) redsum[t >> 6] = lsum;
  __syncthreads();
  float inv = 1.f / (redsum[0] + redsum[1] + redsum[2] + redsum[3]);
#pragma unroll
  for (int j = 0; j < 8; ++j) alpha[b * SEQ + t + j * 256] = ev[j] * inv;
}

// ---------------------------------------------------------------------------
// Kernel 4 (primary): context from fp32 enc, atomic-free. grid (64,8) x 512.
// ---------------------------------------------------------------------------
__global__ __launch_bounds__(512) void context_f32_kernel(
    const float* __restrict__ enc, const float* __restrict__ alpha,
    float* __restrict__ out)
{
  __shared__ float red[16][128];
  int b = blockIdx.x, kc = blockIdx.y, t = threadIdx.x;
  int kl = (t & 31) * 4;              // k-local 0..124
  int strip = t >> 5;                 // 0..15
  const float* ep = enc + ((size_t)b * SEQ + strip * 128) * 1024 + kc * 128 + kl;
  const float* ap = alpha + b * SEQ + strip * 128;
  float a0 = 0.f, a1 = 0.f, a2 = 0.f, a3 = 0.f;
#pragma unroll 4
  for (int s = 0; s < 128; ++s) {
    float a = ap[s];
    float4 v = *(const float4*)(ep + (size_t)s * 1024);
    a0 += a * v.x; a1 += a * v.y; a2 += a * v.z; a3 += a * v.w;
  }
  red[strip][kl + 0] = a0;
  red[strip][kl + 1] = a1;
  red[strip][kl + 2] = a2;
  red[strip][kl + 3] = a3;
  __syncthreads();
  if (t < 128) {
    float s = 0.f;
#pragma unroll
    for (int j = 0; j < 16; ++j) s += red[j][t];
    out[b * 1024 + kc * 128 + t] = s;
  }
}

// ---------------------------------------------------------------------------
// Kernel 4 (fallback): fp32 context with atomics.
// ---------------------------------------------------------------------------
__global__ __launch_bounds__(256) void context_kernel(
    const float* __restrict__ enc, const float* __restrict__ alpha,
    float* __restrict__ out)
{
  int b = blockIdx.y, sq = blockIdx.z, t = threadIdx.x;
  int k4 = t * 4;
  const float* ep = enc + ((size_t)b * SEQ + sq * 128) * 1024 + k4;
  const float* ap = alpha + b * SEQ + sq * 128;
  float ax = 0.f, ay = 0.f, az = 0.f, aw = 0.f;
#pragma unroll 4
  for (int s = 0; s < 128; ++s) {
    float a = ap[s];
    float4 v = *(const float4*)(ep + (size_t)s * 1024);
    ax += a * v.x; ay += a * v.y; az += a * v.z; aw += a * v.w;
  }
  float* o = out + b * 1024 + k4;
  atomicAdd(o + 0, ax);
  atomicAdd(o + 1, ay);
  atomicAdd(o + 2, az);
  atomicAdd(o + 3, aw);
}

// ---------------------------------------------------------------------------
extern "C" void kernel_launch(void* const* d_in, const int* in_sizes, int n_in,
                              void* d_out, int out_size, void* d_ws, size_t ws_size,
                              hipStream_t stream) {
  const float* hid = (const float*)d_in[0];
  const float* enc = (const float*)d_in[1];
  const float* W1  = (const float*)d_in[2];
  const float* b1  = (const float*)d_in[3];
  const float* W2  = (const float*)d_in[4];
  float* out = (float*)d_out;

  float* epart = (float*)d_ws;                       // NB * M_TOT planes
  float* alpha = epart + (size_t)NB * M_TOT;         // M_TOT
  float* hvec  = alpha + M_TOT;                      // 64*1024
  size_t small_bytes = ((size_t)NB * M_TOT + M_TOT + 64 * 1024) * 4;
  size_t w1eb_off = ((small_bytes + 255) / 256) * 256;
  size_t need = w1eb_off + (size_t)1024 * 1024 * 2;  // frag-order W1eB only

  hvec_kernel<<<dim3(64, 64), 256, 0, stream>>>(hid, W1, b1, hvec);

  if (ws_size >= need) {
    unsigned short* W1eB = (unsigned short*)((char*)d_ws + w1eb_off);
    convert_w1e_frag_kernel<<<512, 256, 0, stream>>>(W1, (unsigned int*)W1eB);
    gemm_fused_kernel<<<4096, 512, 0, stream>>>(enc, W1eB, W2, hvec, epart);
    softmax_kernel<<<64, 256, 0, stream>>>(epart, alpha);
    context_f32_kernel<<<dim3(64, 8), 512, 0, stream>>>(enc, alpha, out);
  } else {
    hipMemsetAsync(d_out, 0, (size_t)out_size * sizeof(float), stream);
    fused_gemm_kernel<<<dim3(NB, 1024), 256, 0, stream>>>(enc, W1, W2, hvec, epart);
    softmax_kernel<<<64, 256, 0, stream>>>(epart, alpha);
    context_kernel<<<dim3(1, 64, 16), 256, 0, stream>>>(enc, alpha, out);
  }
}